// Round 1
// baseline (6322.485 us; speedup 1.0000x reference)
//
#include <hip/hip_runtime.h>

#define SEQ  8192
#define HID  100
#define G4   400      // 4*HID gate rows
#define NCLS 20

// ---------- fast activations (v_exp_f32-based) ----------
__device__ __forceinline__ float fast_sigmoid(float x) {
    return 1.0f / (1.0f + __expf(-x));
}
__device__ __forceinline__ float fast_tanh(float x) {
    // tanh(x) = 1 - 2/(exp(2x)+1); saturates correctly at +/-inf
    float e = __expf(2.0f * x);
    return 1.0f - 2.0f / (e + 1.0f);
}

// Raw barrier: waits LDS ops only (lgkmcnt), does NOT drain vmcnt --
// keeps the x_proj prefetch loads in flight across step barriers.
// (__syncthreads would emit s_waitcnt vmcnt(0) and serialize on HBM.)
__device__ __forceinline__ void wg_barrier() {
    asm volatile("s_waitcnt lgkmcnt(0)" ::: "memory");
    __builtin_amdgcn_s_barrier();
    asm volatile("" ::: "memory");
}

// ---------------------------------------------------------------------------
// Kernel 1: x_proj[t][j] = dot(emb[seq[t]], W_ih[j]) + b_ih[j] + b_hh[j]
// 8 timesteps per block; emb rows staged in LDS, broadcast-read.
// ---------------------------------------------------------------------------
__global__ __launch_bounds__(512)
void xproj_kernel(const int* __restrict__ seq, const float* __restrict__ emb,
                  const float* __restrict__ Wih, const float* __restrict__ bih,
                  const float* __restrict__ bhh, float* __restrict__ xp)
{
    __shared__ float er[8][HID];
    const int tid = threadIdx.x;
    const int t0  = blockIdx.x * 8;

    if (tid < 200) {                       // 8 rows * 25 float4
        int r = tid / 25, q = tid - r * 25;
        int s = seq[t0 + r];
        *(float4*)&er[r][4 * q] = *(const float4*)&emb[(size_t)s * HID + 4 * q];
    }
    __syncthreads();

    const int row = (tid < G4) ? tid : (G4 - 1);
    const float4* wr = (const float4*)(Wih + row * HID);   // 400B-aligned
    const float bias = bih[row] + bhh[row];

    float acc[8];
    #pragma unroll
    for (int u = 0; u < 8; ++u) acc[u] = bias;

    #pragma unroll
    for (int k = 0; k < 25; ++k) {
        float4 wv = wr[k];
        #pragma unroll
        for (int u = 0; u < 8; ++u) {
            float4 ev = *(const float4*)&er[u][4 * k];     // LDS broadcast
            acc[u] = fmaf(wv.x, ev.x, acc[u]);
            acc[u] = fmaf(wv.y, ev.y, acc[u]);
            acc[u] = fmaf(wv.z, ev.z, acc[u]);
            acc[u] = fmaf(wv.w, ev.w, acc[u]);
        }
    }
    if (tid < G4) {
        #pragma unroll
        for (int u = 0; u < 8; ++u)
            xp[(size_t)(t0 + u) * G4 + tid] = acc[u];
    }
}

// ---------------------------------------------------------------------------
// Kernel 2: persistent single-workgroup LSTM scan (8192 sequential steps).
// Thread j (<400) owns gate row j: W_hh row register-resident (25 float4).
// Threads 0..99 own c_j / h_j state. h broadcast via LDS.
// MODE 0: x_proj streamed from d_ws with 8-deep register prefetch ring.
// MODE 1: (ws too small) compute input projection inline per step (slow, correct).
// ---------------------------------------------------------------------------
template<int MODE>
__global__ __launch_bounds__(512, 2)
void lstm_scan(const float* __restrict__ xp,
               const float* __restrict__ Whh,
               const float* __restrict__ fcw, const float* __restrict__ fcb,
               const int* __restrict__ seq, const float* __restrict__ emb,
               const float* __restrict__ Wih, const float* __restrict__ bih,
               const float* __restrict__ bhh,
               float* __restrict__ out)
{
    __shared__ float h_s[128];
    __shared__ float g_s[G4];
    __shared__ float er_s[HID];

    const int tid = threadIdx.x;
    const int row = (tid < G4) ? tid : (G4 - 1);   // clamp: no garbage regs
    const int cls = row / HID;                      // 0=i 1=f 2=g 3=o

    // W_hh row -> 100 VGPRs
    float4 w[25];
    {
        const float4* wr = (const float4*)(Whh + row * HID);
        #pragma unroll
        for (int k = 0; k < 25; ++k) w[k] = wr[k];
    }
    float bias2 = 0.0f;
    if constexpr (MODE == 1) bias2 = bih[row] + bhh[row];

    if (tid < 128) h_s[tid] = 0.0f;
    float c = 0.0f;

    float xn[8];
    if constexpr (MODE == 0) {
        #pragma unroll
        for (int u = 0; u < 8; ++u)
            xn[u] = (tid < G4) ? xp[u * G4 + tid] : 0.0f;
    }
    wg_barrier();

    #pragma unroll 1
    for (int t8 = 0; t8 < SEQ; t8 += 8) {
        #pragma unroll
        for (int u = 0; u < 8; ++u) {
            const int t = t8 + u;
            float xcur;
            if constexpr (MODE == 0) {
                xcur = xn[u];
                // prefetch 8 steps ahead; stays in flight across raw barriers
                if (t8 + 8 < SEQ && tid < G4)
                    xn[u] = xp[(size_t)(t + 8) * G4 + tid];
            } else {
                int s = seq[t];
                if (tid < 25)
                    *(float4*)&er_s[4 * tid] =
                        *(const float4*)&emb[(size_t)s * HID + 4 * tid];
                wg_barrier();
                xcur = bias2;
                const float4* xr = (const float4*)(Wih + row * HID);
                #pragma unroll
                for (int k = 0; k < 25; ++k) {
                    float4 wv = xr[k];
                    float4 ev = *(const float4*)&er_s[4 * k];
                    xcur = fmaf(wv.x, ev.x, xcur);
                    xcur = fmaf(wv.y, ev.y, xcur);
                    xcur = fmaf(wv.z, ev.z, xcur);
                    xcur = fmaf(wv.w, ev.w, xcur);
                }
            }

            // gates = xcur + W_hh[row] . h   (4 independent FMA chains,
            // float-pair layout to invite v_pk_fma_f32)
            float2 a0 = make_float2(xcur, 0.0f);
            float2 a1 = make_float2(0.0f, 0.0f);
            #pragma unroll
            for (int k = 0; k < 25; ++k) {
                float4 hv = *(const float4*)&h_s[4 * k];   // broadcast read
                a0.x = fmaf(w[k].x, hv.x, a0.x);
                a0.y = fmaf(w[k].y, hv.y, a0.y);
                a1.x = fmaf(w[k].z, hv.z, a1.x);
                a1.y = fmaf(w[k].w, hv.w, a1.y);
            }
            float acc = (a0.x + a1.x) + (a0.y + a1.y);

            float gv = (cls == 2) ? fast_tanh(acc) : fast_sigmoid(acc);
            if (tid < G4) g_s[tid] = gv;
            wg_barrier();                               // gates visible

            if (tid < HID) {
                float gi = g_s[tid];
                float gf = g_s[tid + HID];
                float gg = g_s[tid + 2 * HID];
                float go = g_s[tid + 3 * HID];
                c = fmaf(gf, c, gi * gg);
                h_s[tid] = go * fast_tanh(c);
            }
            wg_barrier();                               // new h visible
        }
    }

    // final FC: out[20] = fc_w @ h_last + fc_b
    if (tid < NCLS) {
        const float* fr = fcw + tid * HID;
        float s0 = fcb[tid];
        #pragma unroll
        for (int k = 0; k < HID; ++k) s0 = fmaf(fr[k], h_s[k], s0);
        out[tid] = s0;
    }
}

// ---------------------------------------------------------------------------
extern "C" void kernel_launch(void* const* d_in, const int* in_sizes, int n_in,
                              void* d_out, int out_size, void* d_ws, size_t ws_size,
                              hipStream_t stream)
{
    const int*   seq = (const int*)d_in[0];
    const float* emb = (const float*)d_in[1];
    const float* Wih = (const float*)d_in[2];
    const float* Whh = (const float*)d_in[3];
    const float* bih = (const float*)d_in[4];
    const float* bhh = (const float*)d_in[5];
    const float* fcw = (const float*)d_in[6];
    const float* fcb = (const float*)d_in[7];
    float* out = (float*)d_out;
    float* xp  = (float*)d_ws;

    const size_t need = (size_t)SEQ * G4 * sizeof(float);
    if (ws_size >= need) {
        xproj_kernel<<<SEQ / 8, 512, 0, stream>>>(seq, emb, Wih, bih, bhh, xp);
        lstm_scan<0><<<1, 512, 0, stream>>>(xp, Whh, fcw, fcb,
                                            seq, emb, Wih, bih, bhh, out);
    } else {
        lstm_scan<1><<<1, 512, 0, stream>>>(nullptr, Whh, fcw, fcb,
                                            seq, emb, Wih, bih, bhh, out);
    }
}

// Round 2
// 5881.120 us; speedup vs baseline: 1.0750x; 1.0750x over previous
//
#include <hip/hip_runtime.h>

#define SEQ  8192
#define HID  100
#define G4   400      // 4*HID gate rows
#define NCLS 20

typedef float v2f __attribute__((ext_vector_type(2)));
typedef float v4f __attribute__((ext_vector_type(4)));

__device__ __forceinline__ float fast_sigmoid(float x) {
    return 1.0f / (1.0f + __expf(-x));
}
__device__ __forceinline__ float fast_tanh(float x) {
    float e = __expf(2.0f * x);          // saturates correctly at +/-inf
    return 1.0f - 2.0f / (e + 1.0f);
}

// Raw barrier: drains LDS ops only (lgkmcnt), NOT vmcnt — prefetch global
// loads stay in flight across step barriers. (__syncthreads would emit
// s_waitcnt vmcnt(0) and put HBM latency on every step's critical path.)
__device__ __forceinline__ void wg_barrier() {
    asm volatile("s_waitcnt lgkmcnt(0)" ::: "memory");
    __builtin_amdgcn_s_barrier();
    asm volatile("" ::: "memory");
}

// ---------------------------------------------------------------------------
// Kernel 1: x_proj[t][j] = dot(emb[seq[t]], W_ih[j]) + b_ih[j] + b_hh[j]
// 16 timesteps per block. Output stored PERMUTED: gate row j = c*100+r goes
// to slot r*4+c, so the scan kernel (thread tid -> gate row (tid&3)*100 +
// (tid>>2)) reads xp[t*400 + tid] fully coalesced.
// ---------------------------------------------------------------------------
__global__ __launch_bounds__(512)
void xproj_kernel(const int* __restrict__ seq, const float* __restrict__ emb,
                  const float* __restrict__ Wih, const float* __restrict__ bih,
                  const float* __restrict__ bhh, float* __restrict__ xp)
{
    __shared__ float er[16][HID];
    const int tid = threadIdx.x;
    const int t0  = blockIdx.x * 16;

    if (tid < 400) {                       // 16 rows * 25 float4
        int r = tid / 25, q = tid - r * 25;
        int s = seq[t0 + r];
        *(float4*)&er[r][4 * q] = *(const float4*)&emb[(size_t)s * HID + 4 * q];
    }
    __syncthreads();

    const int row = (tid < G4) ? tid : (G4 - 1);
    const float4* wr = (const float4*)(Wih + (size_t)row * HID);
    const float bias = bih[row] + bhh[row];

    float acc[16];
    #pragma unroll
    for (int u = 0; u < 16; ++u) acc[u] = bias;

    #pragma unroll
    for (int k = 0; k < 25; ++k) {
        float4 wv = wr[k];
        #pragma unroll
        for (int u = 0; u < 16; ++u) {
            float4 ev = *(const float4*)&er[u][4 * k];     // LDS broadcast
            acc[u] = fmaf(wv.x, ev.x, acc[u]);
            acc[u] = fmaf(wv.y, ev.y, acc[u]);
            acc[u] = fmaf(wv.z, ev.z, acc[u]);
            acc[u] = fmaf(wv.w, ev.w, acc[u]);
        }
    }
    if (tid < G4) {
        const int cj = row / HID, rj = row - cj * HID;
        const int pj = rj * 4 + cj;                        // permuted slot
        #pragma unroll
        for (int u = 0; u < 16; ++u)
            xp[(size_t)(t0 + u) * G4 + pj] = acc[u];
    }
}

// ---------------------------------------------------------------------------
// Kernel 2: persistent single-workgroup LSTM scan (8192 sequential steps).
// Thread tid: gate class cls=tid&3, state row=tid>>2 -> gate row cls*100+row.
// A row's 4 gates live in 4 ADJACENT LANES -> exchange via shfl_xor (no LDS
// round-trip). h double-buffered in LDS -> ONE barrier per step.
// W_hh row pinned in 100 VGPRs via empty-asm (defeats invariant-load remat,
// the R1 failure: VGPR_Count=80 proved weights were re-streamed from cache).
// ---------------------------------------------------------------------------
template<int MODE>
__global__ __launch_bounds__(512, 2)
void lstm_scan(const float* xp,                      // no __restrict__: pins
               const float* __restrict__ Whh,        // prefetch loads between
               const float* __restrict__ fcw,        // barrier clobbers
               const float* __restrict__ fcb,
               const int* __restrict__ seq, const float* __restrict__ emb,
               const float* __restrict__ Wih, const float* __restrict__ bih,
               const float* __restrict__ bhh,
               float* __restrict__ out)
{
    __shared__ v4f  h4[2][32];        // double-buffered h (128 floats each)
    __shared__ float er_s[HID];       // MODE1 only

    const int tid = threadIdx.x;
    const int cls = tid & 3;                       // 0=i 1=f 2=g 3=o
    const int grp = tid >> 2;                      // 0..127
    const int row = (grp < HID) ? grp : (HID - 1); // clamp idle groups
    const int grow = cls * HID + row;              // gate row in W matrices

    // W_hh row -> 100 VGPRs, pinned (non-rematerializable)
    v4f wv[25];
    {
        const v4f* wr = (const v4f*)(Whh + (size_t)grow * HID);
        #pragma unroll
        for (int k = 0; k < 25; ++k) wv[k] = wr[k];
        #pragma unroll
        for (int k = 0; k < 25; ++k) asm volatile("" : "+v"(wv[k]));
    }
    float bias2 = 0.0f;
    if constexpr (MODE == 1) bias2 = bih[grow] + bhh[grow];

    if (tid < 128) ((float*)h4)[tid] = 0.0f;       // zero h buffer 0
    float c = 0.0f;

    float xn[8];
    if constexpr (MODE == 0) {
        #pragma unroll
        for (int u = 0; u < 8; ++u)
            xn[u] = (tid < G4) ? xp[u * G4 + tid] : 0.0f;
    }
    wg_barrier();

    #pragma unroll 1
    for (int t8 = 0; t8 < SEQ; t8 += 8) {
        #pragma unroll
        for (int u = 0; u < 8; ++u) {
            const int t = t8 + u;
            float xcur;
            if constexpr (MODE == 0) {
                xcur = xn[u];
                // prefetch 8 steps ahead; no restrict on xp => load cannot
                // sink past the barrier clobbers to its use point
                if (t + 8 < SEQ && tid < G4)
                    xn[u] = xp[(size_t)(t + 8) * G4 + tid];
            } else {
                int s_ = seq[t];
                if (tid < 25)
                    *(float4*)&er_s[4 * tid] =
                        *(const float4*)&emb[(size_t)s_ * HID + 4 * tid];
                wg_barrier();
                xcur = bias2;
                const float4* xr = (const float4*)(Wih + (size_t)grow * HID);
                #pragma unroll
                for (int k = 0; k < 25; ++k) {
                    float4 wq = xr[k];
                    float4 ev = *(const float4*)&er_s[4 * k];
                    xcur = fmaf(wq.x, ev.x, xcur);
                    xcur = fmaf(wq.y, ev.y, xcur);
                    xcur = fmaf(wq.z, ev.z, xcur);
                    xcur = fmaf(wq.w, ev.w, xcur);
                }
            }

            // gates = xcur + W_hh[grow] . h : 4 independent v2f chains
            // (v_pk_fma_f32), h broadcast-read from LDS buffer t&1
            const v4f* hb = h4[u & 1];
            v2f s0 = {xcur, 0.0f}, s1 = {0.0f, 0.0f};
            v2f s2 = {0.0f, 0.0f}, s3 = {0.0f, 0.0f};
            #pragma unroll
            for (int k = 0; k < 25; ++k) {
                v4f hv = hb[k];
                if (k & 1) {
                    s2 = __builtin_elementwise_fma(wv[k].lo, hv.lo, s2);
                    s3 = __builtin_elementwise_fma(wv[k].hi, hv.hi, s3);
                } else {
                    s0 = __builtin_elementwise_fma(wv[k].lo, hv.lo, s0);
                    s1 = __builtin_elementwise_fma(wv[k].hi, hv.hi, s1);
                }
            }
            v2f sr = (s0 + s2) + (s1 + s3);
            float acc = sr.x + sr.y;

            // own-gate activation, then exchange within the 4-lane group
            float a = (cls == 2) ? fast_tanh(acc) : fast_sigmoid(acc);
            float b = __shfl_xor(a, 1);
            float xv = (cls & 1) ? b : a;     // i (low pair) / g (high pair)
            float yv = (cls & 1) ? a : b;     // f (low pair) / o (high pair)
            float x2 = __shfl_xor(xv, 2);
            float y2 = __shfl_xor(yv, 2);
            const bool hi = cls >= 2;
            float gi = hi ? x2 : xv, gg = hi ? xv : x2;
            float gf = hi ? y2 : yv, go = hi ? yv : y2;

            // c,h updated redundantly in all 4 lanes (bitwise identical)
            c = fmaf(gf, c, gi * gg);
            float hn = go * fast_tanh(c);
            if (cls == 0 && grp < HID)
                ((float*)h4[(u & 1) ^ 1])[row] = hn;   // write other buffer
            wg_barrier();                               // ONE barrier/step
        }
    }

    // final FC: out[20] = fc_w @ h_last + fc_b   (h_last in buffer 0)
    if (tid < NCLS) {
        const float* hf = (const float*)h4[0];
        const float* fr = fcw + (size_t)tid * HID;
        float s = fcb[tid];
        #pragma unroll
        for (int k = 0; k < HID; ++k) s = fmaf(fr[k], hf[k], s);
        out[tid] = s;
    }
}

// ---------------------------------------------------------------------------
extern "C" void kernel_launch(void* const* d_in, const int* in_sizes, int n_in,
                              void* d_out, int out_size, void* d_ws, size_t ws_size,
                              hipStream_t stream)
{
    const int*   seq = (const int*)d_in[0];
    const float* emb = (const float*)d_in[1];
    const float* Wih = (const float*)d_in[2];
    const float* Whh = (const float*)d_in[3];
    const float* bih = (const float*)d_in[4];
    const float* bhh = (const float*)d_in[5];
    const float* fcw = (const float*)d_in[6];
    const float* fcb = (const float*)d_in[7];
    float* out = (float*)d_out;
    float* xp  = (float*)d_ws;

    const size_t need = (size_t)SEQ * G4 * sizeof(float);
    if (ws_size >= need) {
        xproj_kernel<<<SEQ / 16, 512, 0, stream>>>(seq, emb, Wih, bih, bhh, xp);
        lstm_scan<0><<<1, 512, 0, stream>>>(xp, Whh, fcw, fcb,
                                            seq, emb, Wih, bih, bhh, out);
    } else {
        lstm_scan<1><<<1, 512, 0, stream>>>(nullptr, Whh, fcw, fcb,
                                            seq, emb, Wih, bih, bhh, out);
    }
}

// Round 3
// 5868.269 us; speedup vs baseline: 1.0774x; 1.0022x over previous
//
#include <hip/hip_runtime.h>

#define SEQ  8192
#define HID  100
#define G4   400      // 4*HID gate rows
#define NCLS 20

typedef float v2f __attribute__((ext_vector_type(2)));
typedef float v4f __attribute__((ext_vector_type(4)));

__device__ __forceinline__ float fast_sigmoid(float x) {
    return 1.0f / (1.0f + __expf(-x));
}
__device__ __forceinline__ float fast_tanh(float x) {
    float e = __expf(2.0f * x);          // saturates correctly at +/-inf
    return 1.0f - 2.0f / (e + 1.0f);
}

// Raw barrier: drains LDS ops only (lgkmcnt), NOT vmcnt — prefetch global
// loads stay in flight across step barriers.
__device__ __forceinline__ void wg_barrier() {
    asm volatile("s_waitcnt lgkmcnt(0)" ::: "memory");
    __builtin_amdgcn_s_barrier();
    asm volatile("" ::: "memory");
}

// Cross-lane add via DPP quad_perm (VALU pipe — deliberately NOT __shfl_xor,
// which may lower to ds_swizzle and load the shared LDS pipe).
// xor1 = quad_perm(1,0,3,2) = 0xB1 ; xor2 = quad_perm(2,3,0,1) = 0x4E
template<int CTRL>
__device__ __forceinline__ float dpp_add(float x) {
    int p = __builtin_amdgcn_update_dpp(0, __float_as_int(x), CTRL, 0xF, 0xF, true);
    return x + __int_as_float(p);
}
__device__ __forceinline__ float quad_allreduce(float x) {
    return dpp_add<0x4E>(dpp_add<0xB1>(x));
}

// ---------------------------------------------------------------------------
// Kernel 1: x_proj[t][j] = dot(emb[seq[t]], W_ih[j]) + b_ih[j] + b_hh[j]
// Output PERMUTED: gate row j=c*100+r -> slot r*4+c, so the scan thread for
// row r reads one v4f = {i,f,g,o} projections at xp[t*400 + 4r].
// ---------------------------------------------------------------------------
__global__ __launch_bounds__(512)
void xproj_kernel(const int* __restrict__ seq, const float* __restrict__ emb,
                  const float* __restrict__ Wih, const float* __restrict__ bih,
                  const float* __restrict__ bhh, float* __restrict__ xp)
{
    __shared__ float er[16][HID];
    const int tid = threadIdx.x;
    const int t0  = blockIdx.x * 16;

    if (tid < 400) {                       // 16 rows * 25 float4
        int r = tid / 25, q = tid - r * 25;
        int s = seq[t0 + r];
        *(float4*)&er[r][4 * q] = *(const float4*)&emb[(size_t)s * HID + 4 * q];
    }
    __syncthreads();

    const int row = (tid < G4) ? tid : (G4 - 1);
    const float4* wr = (const float4*)(Wih + (size_t)row * HID);
    const float bias = bih[row] + bhh[row];

    float acc[16];
    #pragma unroll
    for (int u = 0; u < 16; ++u) acc[u] = bias;

    #pragma unroll
    for (int k = 0; k < 25; ++k) {
        float4 wv = wr[k];
        #pragma unroll
        for (int u = 0; u < 16; ++u) {
            float4 ev = *(const float4*)&er[u][4 * k];
            acc[u] = fmaf(wv.x, ev.x, acc[u]);
            acc[u] = fmaf(wv.y, ev.y, acc[u]);
            acc[u] = fmaf(wv.z, ev.z, acc[u]);
            acc[u] = fmaf(wv.w, ev.w, acc[u]);
        }
    }
    if (tid < G4) {
        const int cj = row / HID, rj = row - cj * HID;
        const int pj = rj * 4 + cj;                        // permuted slot
        #pragma unroll
        for (int u = 0; u < 16; ++u)
            xp[(size_t)(t0 + u) * G4 + pj] = acc[u];
    }
}

// ---------------------------------------------------------------------------
// Kernel 2: persistent single-workgroup LSTM scan.
// Thread (r = tid>>2, s = tid&3): computes ALL FOUR gate partial dots of
// h-row r over K-slice s (quads {s, s+4, ..., s+20} + quad 24 for s==0).
// -> 7 ds_read_b128 of h per thread reused across 4 gate rows: LDS instr
//    count/step drops 200 -> ~58 (the R2 bottleneck).
// 4-lane reduce via DPP quad_perm (VALU), gates then identical in all 4
// lanes -> redundant act + c/h update, lane s==0 writes h. 1 barrier/step.
// W_hh slice = v4f w[4][7] = 112 VGPRs; amdgpu_waves_per_eu(2,2) gives the
// allocator a 256-VGPR budget (R2's residency failure: VGPR_Count=84).
// ---------------------------------------------------------------------------
template<int MODE>
__global__ __launch_bounds__(512)
__attribute__((amdgpu_waves_per_eu(2, 2)))
void lstm_scan(const float* xp,                      // no __restrict__: keeps
               const float* __restrict__ Whh,        // prefetch loads pinned
               const float* __restrict__ fcw,        // between barriers
               const float* __restrict__ fcb,
               const int* __restrict__ seq, const float* __restrict__ emb,
               const float* __restrict__ Wih, const float* __restrict__ bih,
               const float* __restrict__ bhh,
               float* __restrict__ out)
{
    __shared__ v4f h4[2][32];          // double-buffered h (128 floats each)
    __shared__ v4f er4[25];            // MODE1 only: staged emb row

    const int tid = threadIdx.x;
    const int s   = tid & 3;                        // K-slice
    const int rg  = tid >> 2;                       // 0..127
    const int r   = (rg < HID) ? rg : (HID - 1);    // clamp idle groups
    const bool live = (rg < HID);

    // W_hh K-slice for all 4 gate rows of row r: quad q = s+4j (j<6), 24 (j==6)
    v4f w[4][7];
    #pragma unroll
    for (int c = 0; c < 4; ++c) {
        const float* wr = Whh + (size_t)(c * HID + r) * HID;
        #pragma unroll
        for (int j = 0; j < 7; ++j) {
            const int q = (j < 6) ? (s + 4 * j) : 24;
            v4f t = *(const v4f*)(wr + 4 * q);
            if (j == 6 && s != 0) t = (v4f){0.f, 0.f, 0.f, 0.f};  // tail only s==0
            w[c][j] = t;
        }
    }
    #pragma unroll
    for (int c = 0; c < 4; ++c)
        #pragma unroll
        for (int j = 0; j < 7; ++j)
            asm volatile("" : "+v"(w[c][j]));       // defeat remat/reload

    v4f bias4 = {0.f, 0.f, 0.f, 0.f};
    if constexpr (MODE == 1) {
        #pragma unroll
        for (int c = 0; c < 4; ++c)
            ((float*)&bias4)[c] = bih[c * HID + r] + bhh[c * HID + r];
    }

    if (tid < 128) ((float*)h4)[tid] = 0.0f;        // zero h buffer 0
    float cst = 0.0f;

    v4f xn[8];
    if constexpr (MODE == 0) {
        #pragma unroll
        for (int u = 0; u < 8; ++u)
            xn[u] = *(const v4f*)(xp + (size_t)u * G4 + 4 * r);
    }
    wg_barrier();

    #pragma unroll 1
    for (int t8 = 0; t8 < SEQ; t8 += 8) {
        #pragma unroll
        for (int u = 0; u < 8; ++u) {
            const int t = t8 + u;

            v4f xpv;
            if constexpr (MODE == 0) {
                xpv = xn[u];
                if (t + 8 < SEQ)     // prefetch 8 ahead; in flight across barriers
                    xn[u] = *(const v4f*)(xp + (size_t)(t + 8) * G4 + 4 * r);
            } else {
                xpv = bias4;
                if (tid < 25) {
                    int sq = seq[t];
                    er4[tid] = *(const v4f*)(emb + (size_t)sq * HID + 4 * tid);
                }
                wg_barrier();
            }

            // 4 gate partial dots over this thread's K-slice
            const v4f* hb = h4[t & 1];
            v2f a0 = {0.f,0.f}, a1 = {0.f,0.f}, a2 = {0.f,0.f}, a3 = {0.f,0.f};
            #pragma unroll
            for (int j = 0; j < 7; ++j) {
                const int q = (j < 6) ? (s + 4 * j) : 24;
                v4f hv = hb[q];                      // 4-addr multicast read
                a0 = __builtin_elementwise_fma(w[0][j].lo, hv.lo, a0);
                a0 = __builtin_elementwise_fma(w[0][j].hi, hv.hi, a0);
                a1 = __builtin_elementwise_fma(w[1][j].lo, hv.lo, a1);
                a1 = __builtin_elementwise_fma(w[1][j].hi, hv.hi, a1);
                a2 = __builtin_elementwise_fma(w[2][j].lo, hv.lo, a2);
                a2 = __builtin_elementwise_fma(w[2][j].hi, hv.hi, a2);
                a3 = __builtin_elementwise_fma(w[3][j].lo, hv.lo, a3);
                a3 = __builtin_elementwise_fma(w[3][j].hi, hv.hi, a3);
            }

            if constexpr (MODE == 1) {               // add W_ih part, same slice
                #pragma unroll
                for (int c = 0; c < 4; ++c) {
                    const float* xr = Wih + (size_t)(c * HID + r) * HID;
                    #pragma unroll
                    for (int j = 0; j < 7; ++j) {
                        if (j == 6 && s != 0) continue;
                        const int q = (j < 6) ? (s + 4 * j) : 24;
                        v4f wq = *(const v4f*)(xr + 4 * q);
                        v4f ev = er4[q];
                        v2f* ac = (c == 0) ? &a0 : (c == 1) ? &a1 : (c == 2) ? &a2 : &a3;
                        *ac = __builtin_elementwise_fma(wq.lo, ev.lo, *ac);
                        *ac = __builtin_elementwise_fma(wq.hi, ev.hi, *ac);
                    }
                }
            }

            // horizontal + 4-lane DPP all-reduce (bitwise identical per lane)
            float gi = quad_allreduce(a0.x + a0.y) + xpv.x;
            float gf = quad_allreduce(a1.x + a1.y) + xpv.y;
            float gg = quad_allreduce(a2.x + a2.y) + xpv.z;
            float go = quad_allreduce(a3.x + a3.y) + xpv.w;

            gi = fast_sigmoid(gi);
            gf = fast_sigmoid(gf);
            gg = fast_tanh(gg);
            go = fast_sigmoid(go);

            cst = fmaf(gf, cst, gi * gg);            // replicated x4, consistent
            float hn = go * fast_tanh(cst);
            if (live && s == 0)
                ((float*)h4[(t & 1) ^ 1])[r] = hn;   // write other buffer
            wg_barrier();                            // ONE barrier/step (MODE0)
        }
    }

    // final FC: out[20] = fc_w @ h_last + fc_b   (h_last in buffer 0: SEQ even)
    if (tid < NCLS) {
        const float* hf = (const float*)h4[0];
        const float* fr = fcw + (size_t)tid * HID;
        float acc = fcb[tid];
        #pragma unroll
        for (int k = 0; k < HID; ++k) acc = fmaf(fr[k], hf[k], acc);
        out[tid] = acc;
    }
}

// ---------------------------------------------------------------------------
extern "C" void kernel_launch(void* const* d_in, const int* in_sizes, int n_in,
                              void* d_out, int out_size, void* d_ws, size_t ws_size,
                              hipStream_t stream)
{
    const int*   seq = (const int*)d_in[0];
    const float* emb = (const float*)d_in[1];
    const float* Wih = (const float*)d_in[2];
    const float* Whh = (const float*)d_in[3];
    const float* bih = (const float*)d_in[4];
    const float* bhh = (const float*)d_in[5];
    const float* fcw = (const float*)d_in[6];
    const float* fcb = (const float*)d_in[7];
    float* out = (float*)d_out;
    float* xp  = (float*)d_ws;

    const size_t need = (size_t)SEQ * G4 * sizeof(float);
    if (ws_size >= need) {
        xproj_kernel<<<SEQ / 16, 512, 0, stream>>>(seq, emb, Wih, bih, bhh, xp);
        lstm_scan<0><<<1, 512, 0, stream>>>(xp, Whh, fcw, fcb,
                                            seq, emb, Wih, bih, bhh, out);
    } else {
        lstm_scan<1><<<1, 512, 0, stream>>>(nullptr, Whh, fcw, fcb,
                                            seq, emb, Wih, bih, bhh, out);
    }
}